// Round 6
// baseline (554.766 us; speedup 1.0000x reference)
//
#include <hip/hip_runtime.h>
#include <hip/hip_bf16.h>

// Problem constants
#define B_   8
#define CH   64      // in/out channels
#define H_   256
#define W_   256
#define NPC  524288  // per-channel element count = B*H*W

// Workspace layout (float offsets) — total 2,130,176 floats = 8.1 MB
#define OFF_TWK_C 0        // [256][32]  cos(2*pi*j*k/256), j-major
#define OFF_TWK_S 8192
#define OFF_TKW_C 16384    // [32][256]  k-major
#define OFF_TKW_S 24576
#define OFF_STAT  32768    // sum[64], sumsq[64], scale[64], shift[64]
#define OFF_X     33024    // X  [512][1024] float2 (interleaved re,im)
#define OFF_M     (OFF_X + 1048576)   // M  [512][1024] float2

__device__ __forceinline__ float bfu2f(unsigned short u) {
  return __uint_as_float(((unsigned)u) << 16);
}
__device__ __forceinline__ unsigned short f2bfu(float f) {
  unsigned u = __float_as_uint(f);
  u += 0x7fffu + ((u >> 16) & 1u);   // round-to-nearest-even
  return (unsigned short)(u >> 16);
}
__device__ __forceinline__ float gelu_f(float v) {
  return 0.5f * v * (1.0f + erff(v * 0.70710678118654752440f));
}

// ---------------------------------------------------------------- K0: init
__global__ void k0_init(float* __restrict__ ws) {
  int idx = blockIdx.x * 256 + threadIdx.x;   // 0..8191
  int j = idx >> 5, k = idx & 31;
  double ang = (6.283185307179586476925286766559 / 256.0) * (double)((j * k) & 255);
  float c = (float)cos(ang), s = (float)sin(ang);
  ws[OFF_TWK_C + j * 32 + k] = c;
  ws[OFF_TWK_S + j * 32 + k] = s;
  ws[OFF_TKW_C + k * 256 + j] = c;
  ws[OFF_TKW_S + k * 256 + j] = s;
  if (idx < 256) ws[OFF_STAT + idx] = 0.0f;
}

// ------------------------- K1: fused forward W-DFT + H-DFT + BN stats
// One block per (b,c). Streams 8 chunks of 32 h-rows through LDS; Xw kept in
// LDS only. Produces X[bc][ky*32+kx] (float2) and BN sum/sumsq atomics.
__global__ __launch_bounds__(256) void k1_fwd(const float* __restrict__ x,
                                              float* __restrict__ ws) {
  __shared__ float  xs[32 * 256];   // 32 KB: current 32-row chunk
  __shared__ float2 xw[32 * 32];    // 8 KB : W-DFT of chunk
  __shared__ float  red[8];
  int bc = blockIdx.x;              // 0..511 = b*64+c
  int tid = threadIdx.x;
  const float* xbase = x + ((size_t)bc << 16);   // 65536 floats per (b,c)

  int kx = tid & 31, rg = tid >> 5;   // W-DFT role: 4 rows each
  int ky = tid >> 3, kxq = tid & 7;   // H-DFT role: kx = kxq*4..+3

  const float* twc = ws + OFF_TWK_C;
  const float* twsn = ws + OFF_TWK_S;

  float accXR[4] = {0.f, 0.f, 0.f, 0.f};
  float accXI[4] = {0.f, 0.f, 0.f, 0.f};
  float st1 = 0.f, st2 = 0.f;

  for (int ch = 0; ch < 8; ++ch) {
    // ---- stage 32 rows (8192 floats) + BN partials
    const float* src = xbase + ch * 32 * 256;
    for (int it = 0; it < 8; ++it) {
      int e4 = it * 256 + tid;                       // float4 idx 0..2047
      float4 v = ((const float4*)src)[e4];
      ((float4*)xs)[e4] = v;
      st1 += v.x + v.y + v.z + v.w;
      st2 += v.x * v.x + v.y * v.y + v.z * v.z + v.w * v.w;
    }
    __syncthreads();   // xs ready

    // ---- W-DFT: rows rg*4..+3 -> xw  (e^{-2pi i kx w/256})
    float aR[4] = {0.f, 0.f, 0.f, 0.f};
    float aI[4] = {0.f, 0.f, 0.f, 0.f};
    for (int w4 = 0; w4 < 256; w4 += 4) {
      float c0 = twc[(w4 + 0) * 32 + kx], c1 = twc[(w4 + 1) * 32 + kx];
      float c2 = twc[(w4 + 2) * 32 + kx], c3 = twc[(w4 + 3) * 32 + kx];
      float n0 = twsn[(w4 + 0) * 32 + kx], n1 = twsn[(w4 + 1) * 32 + kx];
      float n2 = twsn[(w4 + 2) * 32 + kx], n3 = twsn[(w4 + 3) * 32 + kx];
#pragma unroll
      for (int r = 0; r < 4; ++r) {
        float4 xv = *(const float4*)(xs + (rg * 4 + r) * 256 + w4);
        aR[r] += xv.x * c0 + xv.y * c1 + xv.z * c2 + xv.w * c3;
        aI[r] -= xv.x * n0 + xv.y * n1 + xv.z * n2 + xv.w * n3;
      }
    }
#pragma unroll
    for (int r = 0; r < 4; ++r)
      xw[(rg * 4 + r) * 32 + kx] = make_float2(aR[r], aI[r]);
    __syncthreads();   // xw ready

    // ---- H-DFT accumulate: X[ky][kx] += sum_h xw[h][kx] e^{-2pi i ky h/256}
    for (int hh = 0; hh < 32; ++hh) {
      int h = ch * 32 + hh;
      float c = twc[h * 32 + ky], s = twsn[h * 32 + ky];
#pragma unroll
      for (int j = 0; j < 4; ++j) {
        float2 v = xw[hh * 32 + kxq * 4 + j];
        accXR[j] += v.x * c + v.y * s;     // (vx+ivy)(c-is): re
        accXI[j] += v.y * c - v.x * s;     //                 im
      }
    }
    __syncthreads();   // xw/xs consumed; safe to overwrite next chunk
  }

  // ---- BN stats reduction -> atomics
  for (int off = 32; off; off >>= 1) {
    st1 += __shfl_down(st1, off);
    st2 += __shfl_down(st2, off);
  }
  int wid = tid >> 6;
  if ((tid & 63) == 0) { red[wid * 2] = st1; red[wid * 2 + 1] = st2; }
  __syncthreads();
  if (tid == 0) {
    float a = red[0] + red[2] + red[4] + red[6];
    float b2 = red[1] + red[3] + red[5] + red[7];
    int c = bc & 63;
    atomicAdd(&ws[OFF_STAT + c], a);
    atomicAdd(&ws[OFF_STAT + 64 + c], b2);
  }

  // ---- write X (float2 interleaved)
  float2* X2 = (float2*)(ws + OFF_X);
  int m0 = ky * 32 + kxq * 4;
#pragma unroll
  for (int j = 0; j < 4; ++j)
    X2[((size_t)bc << 10) + m0 + j] = make_float2(accXR[j], accXI[j]);
}

// ------------------------------------------------------- K1b: finalize BN
__global__ void k1b_stats(const float* __restrict__ g, const float* __restrict__ b,
                          float* __restrict__ ws) {
  int c = threadIdx.x;   // 64
  float mean = ws[OFF_STAT + c] * (1.0f / NPC);
  float var = ws[OFF_STAT + 64 + c] * (1.0f / NPC) - mean * mean;
  float rstd = rsqrtf(var + 1e-5f);
  float sc = g[c] * rstd;
  ws[OFF_STAT + 128 + c] = sc;
  ws[OFF_STAT + 192 + c] = b[c] - mean * sc;
}

// ---------------------------------------------------------- K2: mode mix
// M[b,o,m] = sum_i X[b,i,m]*W[i,o,m] (complex), scaled by fft_scale/(H*W)*c_kx
__global__ __launch_bounds__(256) void k2_mix(const float* __restrict__ wr,
                                              const float* __restrict__ wi,
                                              const float* __restrict__ fscale,
                                              float* __restrict__ ws) {
  int o = blockIdx.x & 63;
  int mc = blockIdx.x >> 6;                 // 0..15
  int tid = threadIdx.x;
  int m = mc * 64 + (tid & 63);
  int b0 = (tid >> 6) * 2;                  // {0,2,4,6}
  const float2* X2 = (const float2*)(ws + OFF_X);
  float mr0 = 0.f, mi0 = 0.f, mr1 = 0.f, mi1 = 0.f;
#pragma unroll 2
  for (int i = 0; i < 64; ++i) {
    float wre = wr[(((size_t)(i << 6) + o) << 10) + m];
    float wim = wi[(((size_t)(i << 6) + o) << 10) + m];
    float2 x0 = X2[(((size_t)(b0 << 6) + i) << 10) + m];
    float2 x1 = X2[(((size_t)((b0 + 1) << 6) + i) << 10) + m];
    mr0 += x0.x * wre - x0.y * wim;
    mi0 += x0.x * wim + x0.y * wre;
    mr1 += x1.x * wre - x1.y * wim;
    mi1 += x1.x * wim + x1.y * wre;
  }
  float fs = fscale[0] * (1.0f / 65536.0f);
  if (m & 31) fs *= 2.0f;                    // irfft kx-weight (c0=1, else 2)
  float2* M2 = (float2*)(ws + OFF_M);
  M2[(((size_t)(b0 << 6) + o) << 10) + m] = make_float2(mr0 * fs, mi0 * fs);
  M2[(((size_t)((b0 + 1) << 6) + o) << 10) + m] = make_float2(mr1 * fs, mi1 * fs);
}

// ------ K3: fused inverse H-DFT + inverse W-DFT + BN+GELU+1x1 conv + skip
// One block per (b,h). T[o,kx] computed on the fly from M (L2/L3-resident).
// Output is float32 (the reference's output dtype).
__global__ __launch_bounds__(256) void k3_final(const float* __restrict__ x,
                                                const float* __restrict__ pw,
                                                const float* __restrict__ pb,
                                                const float* __restrict__ ws,
                                                float* __restrict__ out) {
  __shared__ float2 tl[64 * 32];           // 16 KB  T slice for this (b,h)
  __shared__ unsigned short gl[64 * 256];  // 32 KB  gelu(bn(x)) in bf16
  __shared__ float scll[64], sftl[64];
  int bh = blockIdx.x;                     // 2048 = b*256 + h
  int b = bh >> 8, h = bh & 255;
  int tid = threadIdx.x;

  // ---- inverse H-DFT: T[o,kx] = sum_ky M[b,o,ky,kx] e^{+2pi i ky h/256}
  {
    int o = tid >> 2, kx0 = (tid & 3) * 8;  // each thread: 8 kx for one o
    const float2* Mrow = (const float2*)(ws + OFF_M) + (((size_t)(b * 64 + o)) << 10);
    const float* twc = ws + OFF_TWK_C;
    const float* twsn = ws + OFF_TWK_S;
    float tr[8] = {0.f, 0.f, 0.f, 0.f, 0.f, 0.f, 0.f, 0.f};
    float ti[8] = {0.f, 0.f, 0.f, 0.f, 0.f, 0.f, 0.f, 0.f};
    for (int ky = 0; ky < 32; ++ky) {
      float c = twc[h * 32 + ky], s = twsn[h * 32 + ky];
#pragma unroll
      for (int j = 0; j < 8; ++j) {
        float2 mv = Mrow[ky * 32 + kx0 + j];
        tr[j] += mv.x * c - mv.y * s;      // (mx+imy)(c+is): re
        ti[j] += mv.x * s + mv.y * c;      //                 im
      }
    }
#pragma unroll
    for (int j = 0; j < 8; ++j) tl[o * 32 + kx0 + j] = make_float2(tr[j], ti[j]);
  }
  if (tid < 64) {
    scll[tid] = ws[OFF_STAT + 128 + tid];
    sftl[tid] = ws[OFF_STAT + 192 + tid];
  }
  __syncthreads();

  // ---- stage gelu(bn(x)) for all 64 in-channels of this (b,h) row
  const float* xsl = x + (((size_t)b * 64) << 16) + ((size_t)h << 8);
  for (int it = 0; it < 16; ++it) {
    int e4 = it * 256 + tid;          // 0..4095
    int i = e4 >> 6;
    int wq = (e4 & 63) << 2;
    float4 v = *(const float4*)(xsl + ((size_t)i << 16) + wq);
    float a = scll[i], sh = sftl[i];
    ushort4 gq;
    gq.x = f2bfu(gelu_f(v.x * a + sh));
    gq.y = f2bfu(gelu_f(v.y * a + sh));
    gq.z = f2bfu(gelu_f(v.z * a + sh));
    gq.w = f2bfu(gelu_f(v.w * a + sh));
    *(ushort4*)&gl[i * 256 + wq] = gq;
  }
  __syncthreads();

  // ---- accumulate: pb + invW(T) + conv(g, pw) + x  -> fp32 store
  int w4 = (tid & 63) << 2;
  int ob = __builtin_amdgcn_readfirstlane(tid >> 6) << 4;   // wave-uniform o-base
  float4 acc[16];
#pragma unroll
  for (int oi = 0; oi < 16; ++oi) {
    float pbv = pb[ob + oi];
    acc[oi] = make_float4(pbv, pbv, pbv, pbv);
  }

  const float* tkc = ws + OFF_TKW_C;
  const float* tks = ws + OFF_TKW_S;
  for (int kxx = 0; kxx < 32; ++kxx) {
    float4 c4 = *(const float4*)(tkc + (kxx << 8) + w4);
    float4 s4 = *(const float4*)(tks + (kxx << 8) + w4);
#pragma unroll
    for (int oi = 0; oi < 16; ++oi) {
      float2 t = tl[((ob + oi) << 5) + kxx];
      acc[oi].x += t.x * c4.x - t.y * s4.x;
      acc[oi].y += t.x * c4.y - t.y * s4.y;
      acc[oi].z += t.x * c4.z - t.y * s4.z;
      acc[oi].w += t.x * c4.w - t.y * s4.w;
    }
  }

  for (int i = 0; i < 64; ++i) {
    ushort4 gb = *(const ushort4*)&gl[(i << 8) + w4];
    float g0 = bfu2f(gb.x), g1 = bfu2f(gb.y), g2 = bfu2f(gb.z), g3 = bfu2f(gb.w);
#pragma unroll
    for (int oi = 0; oi < 16; ++oi) {
      float pv = pw[((ob + oi) << 6) + i];
      acc[oi].x += g0 * pv;
      acc[oi].y += g1 * pv;
      acc[oi].z += g2 * pv;
      acc[oi].w += g3 * pv;
    }
  }

  size_t obase = (((size_t)b * 64) << 16) + ((size_t)h << 8);
#pragma unroll
  for (int oi = 0; oi < 16; ++oi) {
    int o = ob + oi;
    float4 xv = *(const float4*)(xsl + ((size_t)o << 16) + w4);
    float4 r;
    r.x = acc[oi].x + xv.x;
    r.y = acc[oi].y + xv.y;
    r.z = acc[oi].z + xv.z;
    r.w = acc[oi].w + xv.w;
    *(float4*)(out + obase + ((size_t)o << 16) + w4) = r;
  }
}

// ---------------------------------------------------------------- launcher
extern "C" void kernel_launch(void* const* d_in, const int* in_sizes, int n_in,
                              void* d_out, int out_size, void* d_ws, size_t ws_size,
                              hipStream_t stream) {
  const float* x  = (const float*)d_in[0];
  const float* wr = (const float*)d_in[1];
  const float* wi = (const float*)d_in[2];
  const float* fs = (const float*)d_in[3];
  const float* bg = (const float*)d_in[4];
  const float* bb = (const float*)d_in[5];
  const float* pw = (const float*)d_in[6];
  const float* pb = (const float*)d_in[7];
  float* ws = (float*)d_ws;
  float* out = (float*)d_out;

  hipLaunchKernelGGL(k0_init,   dim3(32),   dim3(256), 0, stream, ws);
  hipLaunchKernelGGL(k1_fwd,    dim3(512),  dim3(256), 0, stream, x, ws);
  hipLaunchKernelGGL(k1b_stats, dim3(1),    dim3(64),  0, stream, bg, bb, ws);
  hipLaunchKernelGGL(k2_mix,    dim3(1024), dim3(256), 0, stream, wr, wi, fs, ws);
  hipLaunchKernelGGL(k3_final,  dim3(2048), dim3(256), 0, stream, x, pw, pb, ws, out);
}